// Round 7
// baseline (205.939 us; speedup 1.0000x reference)
//
#include <hip/hip_runtime.h>
#include <math.h>

#define BB 4
#define SS 2048
#define DD 768
#define HH 12
#define KK 64

#define NPROJ 3
#define HK    (HH * KK)          // 768
#define NCOLS (NPROJ * HK)       // 2304
#define MROWS (BB * SS)          // 8192
#define PER   (BB * HH * SS * KK)  // 6291456 elements per proj

typedef __attribute__((ext_vector_type(8))) short bf16x8;
typedef __attribute__((ext_vector_type(4))) short bf16x4;
typedef __attribute__((ext_vector_type(4))) float f32x4;
typedef __attribute__((ext_vector_type(16))) float f32x16;

static __device__ __forceinline__ short f2bf(float f) {
  union { float f; unsigned u; } v;
  v.f = f;
  unsigned r = (v.u + 0x7fff + ((v.u >> 16) & 1)) >> 16;  // RNE
  return (short)r;
}

static __device__ __forceinline__ unsigned cvtpk(float lo, float hi) {
  unsigned r;
  asm("v_cvt_pk_bf16_f32 %0, %1, %2" : "=v"(r) : "v"(lo), "v"(hi));
  return r;
}

static __device__ __forceinline__ float fexp2(float x) {
#if __has_builtin(__builtin_amdgcn_exp2f)
  return __builtin_amdgcn_exp2f(x);
#else
  return exp2f(x);
#endif
}

// ---------------------------------------------------------------------------
// x (fp32) -> bf16, flat copy. 4 elems/thread.
// ---------------------------------------------------------------------------
__global__ __launch_bounds__(256) void conv_x(const float* __restrict__ x,
                                              short* __restrict__ xbf) {
  int i = (blockIdx.x * 256 + threadIdx.x) * 4;
  float4 v = *(const float4*)(x + i);
  bf16x4 o = {f2bf(v.x), f2bf(v.y), f2bf(v.z), f2bf(v.w)};
  *(bf16x4*)(xbf + i) = o;
}

// ---------------------------------------------------------------------------
// W -> bf16 transposed wT[n][d]. Q gets 1/sqrt(64) * log2(e) folded in
// (softmax runs in exp2 domain).
// ---------------------------------------------------------------------------
__global__ __launch_bounds__(256) void conv_w(const float* __restrict__ Wq,
                                              const float* __restrict__ Wk,
                                              const float* __restrict__ Wv,
                                              short* __restrict__ wbf) {
  int o = blockIdx.x * 256 + threadIdx.x;  // 2304*768 total
  int n = o / DD, d = o % DD;
  int proj = n / HK;
  int hk = n % HK;
  int h = hk >> 6, k = hk & 63;
  const float* W = proj == 0 ? Wq : (proj == 1 ? Wk : Wv);
  float v = W[(size_t)h * DD * KK + (size_t)d * KK + k];
  if (proj == 0) v *= 0.125f * 1.44269504088896340736f;
  wbf[o] = f2bf(v);
}

// ---------------------------------------------------------------------------
// QKV GEMM (unchanged): C[m][n] = sum_d xbf[m][d] * wT[n][d].
// V (proj 2) written TRANSPOSED: Vt[bh][k][s].
// ---------------------------------------------------------------------------
__global__ __launch_bounds__(256) void qkv_gemm(const short* __restrict__ xbf,
                                                const short* __restrict__ wbf,
                                                short* __restrict__ qkv) {
  __shared__ short As[128 * 64];
  __shared__ short Bs[128 * 64];
  int bm = blockIdx.x & 63, bn = blockIdx.x >> 6;
  int m0 = bm * 128, n0 = bn * 128;
  int tid = threadIdx.x, lane = tid & 63, wid = tid >> 6;
  int li = lane & 15, lg = lane >> 4;
  int wm = wid >> 1, wn = wid & 1;

  f32x4 acc[4][4];
  #pragma unroll
  for (int mi = 0; mi < 4; ++mi)
    #pragma unroll
    for (int ni = 0; ni < 4; ++ni)
      acc[mi][ni] = (f32x4){0.f, 0.f, 0.f, 0.f};

  int rowoff = lane >> 3;
  int kp = (lane & 7) * 8;

  for (int kt = 0; kt < DD / 64; ++kt) {
    #pragma unroll
    for (int j = 0; j < 4; ++j) {
      int eb = wid * 2048 + j * 512;
      int row = (eb >> 6) + rowoff;
      __builtin_amdgcn_global_load_lds(
          (const __attribute__((address_space(1))) void*)(
              xbf + (size_t)(m0 + row) * DD + kt * 64 + kp),
          (__attribute__((address_space(3))) void*)(As + eb), 16, 0, 0);
      __builtin_amdgcn_global_load_lds(
          (const __attribute__((address_space(1))) void*)(
              wbf + (size_t)(n0 + row) * DD + kt * 64 + kp),
          (__attribute__((address_space(3))) void*)(Bs + eb), 16, 0, 0);
    }
    __syncthreads();

    #pragma unroll
    for (int kk = 0; kk < 2; ++kk) {
      bf16x8 af[4], bfr[4];
      #pragma unroll
      for (int mi = 0; mi < 4; ++mi)
        af[mi] = *(const bf16x8*)(As + (wm * 64 + mi * 16 + li) * 64 +
                                  kk * 32 + lg * 8);
      #pragma unroll
      for (int ni = 0; ni < 4; ++ni)
        bfr[ni] = *(const bf16x8*)(Bs + (wn * 64 + ni * 16 + li) * 64 +
                                   kk * 32 + lg * 8);
      #pragma unroll
      for (int mi = 0; mi < 4; ++mi)
        #pragma unroll
        for (int ni = 0; ni < 4; ++ni)
          acc[mi][ni] = __builtin_amdgcn_mfma_f32_16x16x32_bf16(
              af[mi], bfr[ni], acc[mi][ni], 0, 0, 0);
    }
    __syncthreads();
  }

  int proj = n0 / HK;
  #pragma unroll
  for (int ni = 0; ni < 4; ++ni) {
    int ncol = n0 + wn * 64 + ni * 16 + li;
    int hk = ncol % HK;
    int h = hk >> 6, k = hk & 63;
    #pragma unroll
    for (int mi = 0; mi < 4; ++mi) {
      int mrow0 = m0 + wm * 64 + mi * 16 + lg * 4;
      int b = mrow0 >> 11, s = mrow0 & 2047;
      if (proj == 2) {
        bf16x4 o = {f2bf(acc[mi][ni][0]), f2bf(acc[mi][ni][1]),
                    f2bf(acc[mi][ni][2]), f2bf(acc[mi][ni][3])};
        *(bf16x4*)(qkv + 2 * (size_t)PER +
                   ((size_t)(b * HH + h) * KK + k) * SS + s) = o;
      } else {
        #pragma unroll
        for (int r = 0; r < 4; ++r)
          qkv[(size_t)proj * PER +
              ((size_t)(b * HH + h) * SS + s + r) * KK + k] =
              f2bf(acc[mi][ni][r]);
      }
    }
  }
}

// ---------------------------------------------------------------------------
// One 32x32 flash step (exp2 domain, defer-max THR=11).
// sc C-layout: col=lane&31=q, row=key=crow(r,hi)=(r&3)+8*(r>>2)+4*hi.
// ---------------------------------------------------------------------------
static __device__ __forceinline__ void attn_step(
    const bf16x8* kf, const bf16x8 (*vf)[2], const bf16x8* qf, bool diag,
    int lq, int hi, float& m, float& lsum, f32x16& acc0, f32x16& acc1) {
  f32x16 sc;
  #pragma unroll
  for (int r = 0; r < 16; ++r) sc[r] = 0.f;
  #pragma unroll
  for (int c = 0; c < 4; ++c)
    sc = __builtin_amdgcn_mfma_f32_32x32x16_bf16(kf[c], qf[c], sc, 0, 0, 0);

  if (diag) {
    #pragma unroll
    for (int r = 0; r < 16; ++r) {
      int crow = (r & 3) + 8 * (r >> 2) + 4 * hi;
      if (crow > lq) sc[r] = -INFINITY;
    }
  }

  // max: pairwise tree
  float t8[8];
  #pragma unroll
  for (int r = 0; r < 8; ++r) t8[r] = fmaxf(sc[2 * r], sc[2 * r + 1]);
  float t4a = fmaxf(t8[0], t8[1]), t4b = fmaxf(t8[2], t8[3]);
  float t4c = fmaxf(t8[4], t8[5]), t4d = fmaxf(t8[6], t8[7]);
  float tm = fmaxf(fmaxf(t4a, t4b), fmaxf(t4c, t4d));
  tm = fmaxf(tm, __shfl_xor(tm, 32, 64));

  if (!__all(tm <= m + 11.f)) {  // defer-max (exp2 domain)
    float nm = fmaxf(m, tm);
    float corr = fexp2(m - nm);
    m = nm;
    lsum *= corr;
    #pragma unroll
    for (int r = 0; r < 16; ++r) {
      acc0[r] *= corr;
      acc1[r] *= corr;
    }
  }

  float p[16];
  #pragma unroll
  for (int r = 0; r < 16; ++r) p[r] = fexp2(sc[r] - m);
  float s8[8];
  #pragma unroll
  for (int r = 0; r < 8; ++r) s8[r] = p[2 * r] + p[2 * r + 1];
  float s4a = s8[0] + s8[1], s4b = s8[2] + s8[3];
  float s4c = s8[4] + s8[5], s4d = s8[6] + s8[7];
  float ps = (s4a + s4b) + (s4c + s4d);
  ps += __shfl_xor(ps, 32, 64);
  lsum += ps;

  // P fragments (B of O^T): cvt_pk + permlane32_swap
  bf16x8 pf[2];
  #pragma unroll
  for (int c = 0; c < 2; ++c) {
    unsigned a0 = cvtpk(p[8 * c + 0], p[8 * c + 1]);
    unsigned b0 = cvtpk(p[8 * c + 4], p[8 * c + 5]);
    unsigned a1 = cvtpk(p[8 * c + 2], p[8 * c + 3]);
    unsigned b1 = cvtpk(p[8 * c + 6], p[8 * c + 7]);
    asm volatile("v_permlane32_swap_b32 %0, %1" : "+v"(a0), "+v"(b0));
    asm volatile("v_permlane32_swap_b32 %0, %1" : "+v"(a1), "+v"(b1));
    union { unsigned u[4]; bf16x8 v; } pu;
    pu.u[0] = a0; pu.u[1] = a1; pu.u[2] = b0; pu.u[3] = b1;
    pf[c] = pu.v;
  }

  acc0 = __builtin_amdgcn_mfma_f32_32x32x16_bf16(vf[0][0], pf[0], acc0, 0, 0, 0);
  acc0 = __builtin_amdgcn_mfma_f32_32x32x16_bf16(vf[0][1], pf[1], acc0, 0, 0, 0);
  acc1 = __builtin_amdgcn_mfma_f32_32x32x16_bf16(vf[1][0], pf[0], acc1, 0, 0, 0);
  acc1 = __builtin_amdgcn_mfma_f32_32x32x16_bf16(vf[1][1], pf[1], acc1, 0, 0, 0);
}

// ---------------------------------------------------------------------------
// Flash attention, 32x32 MFMA, intra-block 8-way split-K (2 chains/wave).
// Block = one 32-query group; wave w runs chain A (tiles ≡ w mod 8) and
// chain B (tiles ≡ w+4 mod 8) with independent online-softmax state —
// two register-independent MFMA/VALU chains per wave for ILP. Chains merged
// in-register, then 4 wave-partials merged via LDS (flash-decode combine).
// ---------------------------------------------------------------------------
__global__ __launch_bounds__(256, 3) void attn_kernel(
    const short* __restrict__ qkv, float* __restrict__ out) {
  __shared__ float accL[4][32][68];
  __shared__ float mlL[4][2][32];

  int wid = threadIdx.x >> 6, lane = threadIdx.x & 63;
  int bh = blockIdx.x % 48;          // qg-major: heaviest groups first
  int qg = 63 - (blockIdx.x / 48);
  int b = bh / HH, h = bh % HH;
  int s0 = qg * 32;
  int lq = lane & 31;                // query column
  int hi = lane >> 5;

  const short* Qb = qkv + (size_t)bh * SS * KK;
  const short* Kb = qkv + (size_t)PER + (size_t)bh * SS * KK;
  const short* Vt = qkv + 2 * (size_t)PER + (size_t)bh * KK * SS;

  bf16x8 qf[4];
  #pragma unroll
  for (int c = 0; c < 4; ++c)
    qf[c] = *(const bf16x8*)(Qb + (size_t)(s0 + lq) * KK + c * 16 + hi * 8);

  f32x16 aA0, aA1, aB0, aB1;
  #pragma unroll
  for (int r = 0; r < 16; ++r) { aA0[r] = 0.f; aA1[r] = 0.f; aB0[r] = 0.f; aB1[r] = 0.f; }
  float mA = -INFINITY, lA = 0.f, mB = -INFINITY, lB = 0.f;

  int tt0 = wid;
  for (; tt0 + 4 <= qg; tt0 += 8) {
    int tA = tt0 * 32, tB = (tt0 + 4) * 32;
    bf16x8 kfA[4], kfB[4];
    #pragma unroll
    for (int c = 0; c < 4; ++c) {
      kfA[c] = *(const bf16x8*)(Kb + (size_t)(tA + lq) * KK + c * 16 + hi * 8);
      kfB[c] = *(const bf16x8*)(Kb + (size_t)(tB + lq) * KK + c * 16 + hi * 8);
    }
    bf16x8 vfA[2][2], vfB[2][2];
    #pragma unroll
    for (int m2 = 0; m2 < 2; ++m2)
      #pragma unroll
      for (int c = 0; c < 2; ++c) {
        vfA[m2][c] = *(const bf16x8*)(Vt + (size_t)(32 * m2 + lq) * SS + tA +
                                      c * 16 + hi * 8);
        vfB[m2][c] = *(const bf16x8*)(Vt + (size_t)(32 * m2 + lq) * SS + tB +
                                      c * 16 + hi * 8);
      }
    attn_step(kfA, vfA, qf, false, lq, hi, mA, lA, aA0, aA1);
    attn_step(kfB, vfB, qf, tt0 + 4 == qg, lq, hi, mB, lB, aB0, aB1);
  }
  if (tt0 <= qg) {  // peeled tail: chain A only
    int tA = tt0 * 32;
    bf16x8 kfA[4];
    #pragma unroll
    for (int c = 0; c < 4; ++c)
      kfA[c] = *(const bf16x8*)(Kb + (size_t)(tA + lq) * KK + c * 16 + hi * 8);
    bf16x8 vfA[2][2];
    #pragma unroll
    for (int m2 = 0; m2 < 2; ++m2)
      #pragma unroll
      for (int c = 0; c < 2; ++c)
        vfA[m2][c] = *(const bf16x8*)(Vt + (size_t)(32 * m2 + lq) * SS + tA +
                                      c * 16 + hi * 8);
    attn_step(kfA, vfA, qf, tt0 == qg, lq, hi, mA, lA, aA0, aA1);
  }

  // ---- in-register merge of the two chains (guard empty chains) ----
  float M2 = fmaxf(mA, mB);
  float cA = (mA > -INFINITY) ? fexp2(mA - M2) : 0.f;
  float cB = (mB > -INFINITY) ? fexp2(mB - M2) : 0.f;
  float lw = lA * cA + lB * cB;

  // ---- write wave partial: q=lq, kd=32*m2+crow(g-reg,hi) ----
  #pragma unroll
  for (int g = 0; g < 4; ++g) {
    f32x4 v0, v1;
    #pragma unroll
    for (int r = 0; r < 4; ++r) {
      v0[r] = aA0[g * 4 + r] * cA + aB0[g * 4 + r] * cB;
      v1[r] = aA1[g * 4 + r] * cA + aB1[g * 4 + r] * cB;
    }
    *(f32x4*)&accL[wid][lq][8 * g + 4 * hi] = v0;
    *(f32x4*)&accL[wid][lq][32 + 8 * g + 4 * hi] = v1;
  }
  if (hi == 0) {
    mlL[wid][0][lq] = M2;
    mlL[wid][1][lq] = lw;
  }
  __syncthreads();

  // ---- merge (flash-decode combine): wave w -> queries 8w..8w+7 ----
  {
    int q = 8 * wid + (lane >> 3);
    int kd = (lane & 7) * 8;
    float M = -INFINITY;
    #pragma unroll
    for (int v = 0; v < 4; ++v) M = fmaxf(M, mlL[v][0][q]);
    float scw[4], L = 0.f;
    #pragma unroll
    for (int v = 0; v < 4; ++v) {
      scw[v] = fexp2(mlL[v][0][q] - M);
      L += mlL[v][1][q] * scw[v];
    }
    float inv = 1.0f / L;
    float o[8];
    #pragma unroll
    for (int j = 0; j < 8; ++j) o[j] = 0.f;
    #pragma unroll
    for (int v = 0; v < 4; ++v) {
      f32x4 a0 = *(const f32x4*)&accL[v][q][kd];
      f32x4 a1 = *(const f32x4*)&accL[v][q][kd + 4];
      #pragma unroll
      for (int j = 0; j < 4; ++j) {
        o[j] += a0[j] * scw[v];
        o[4 + j] += a1[j] * scw[v];
      }
    }
    float* orow = out + ((size_t)(b * SS + s0 + q)) * HK + h * KK + kd;
    float4 w0 = {o[0] * inv, o[1] * inv, o[2] * inv, o[3] * inv};
    float4 w1 = {o[4] * inv, o[5] * inv, o[6] * inv, o[7] * inv};
    *(float4*)(orow) = w0;
    *(float4*)(orow + 4) = w1;
  }
}

// ---------------------------------------------------------------------------
extern "C" void kernel_launch(void* const* d_in, const int* in_sizes, int n_in,
                              void* d_out, int out_size, void* d_ws,
                              size_t ws_size, hipStream_t stream) {
  const float* x  = (const float*)d_in[0];
  const float* Wq = (const float*)d_in[1];
  const float* Wk = (const float*)d_in[2];
  const float* Wv = (const float*)d_in[3];
  short* ws  = (short*)d_ws;
  short* qkv = ws;                       // 3 * PER shorts
  short* xbf = ws + (size_t)3 * PER;     // MROWS*DD shorts
  short* wbf = xbf + (size_t)MROWS * DD; // NCOLS*DD shorts
  float* o   = (float*)d_out;

  conv_x<<<(MROWS * DD) / 4 / 256, 256, 0, stream>>>(x, xbf);
  conv_w<<<(NCOLS * DD) / 256, 256, 0, stream>>>(Wq, Wk, Wv, wbf);
  qkv_gemm<<<(MROWS / 128) * (NCOLS / 128), 256, 0, stream>>>(xbf, wbf, qkv);
  attn_kernel<<<48 * 64, 256, 0, stream>>>(ws, o);
}

// Round 8
// 190.598 us; speedup vs baseline: 1.0805x; 1.0805x over previous
//
#include <hip/hip_runtime.h>
#include <math.h>

#define BB 4
#define SS 2048
#define DD 768
#define HH 12
#define KK 64

#define NPROJ 3
#define HK    (HH * KK)          // 768
#define NCOLS (NPROJ * HK)       // 2304
#define MROWS (BB * SS)          // 8192
#define PER   (BB * HH * SS * KK)  // 6291456 elements per proj

typedef __attribute__((ext_vector_type(8))) short bf16x8;
typedef __attribute__((ext_vector_type(4))) short bf16x4;
typedef __attribute__((ext_vector_type(4))) float f32x4;
typedef __attribute__((ext_vector_type(16))) float f32x16;

static __device__ __forceinline__ short f2bf(float f) {
  union { float f; unsigned u; } v;
  v.f = f;
  unsigned r = (v.u + 0x7fff + ((v.u >> 16) & 1)) >> 16;  // RNE
  return (short)r;
}

static __device__ __forceinline__ unsigned cvtpk(float lo, float hi) {
  unsigned r;
  asm("v_cvt_pk_bf16_f32 %0, %1, %2" : "=v"(r) : "v"(lo), "v"(hi));
  return r;
}

static __device__ __forceinline__ float fexp2(float x) {
#if __has_builtin(__builtin_amdgcn_exp2f)
  return __builtin_amdgcn_exp2f(x);
#else
  return exp2f(x);
#endif
}

// ---------------------------------------------------------------------------
// x (fp32) -> bf16, flat copy. 4 elems/thread.
// ---------------------------------------------------------------------------
__global__ __launch_bounds__(256) void conv_x(const float* __restrict__ x,
                                              short* __restrict__ xbf) {
  int i = (blockIdx.x * 256 + threadIdx.x) * 4;
  float4 v = *(const float4*)(x + i);
  bf16x4 o = {f2bf(v.x), f2bf(v.y), f2bf(v.z), f2bf(v.w)};
  *(bf16x4*)(xbf + i) = o;
}

// ---------------------------------------------------------------------------
// W -> bf16 transposed wT[n][d]. Q gets 1/sqrt(64) * log2(e) folded in
// (softmax runs in exp2 domain).
// ---------------------------------------------------------------------------
__global__ __launch_bounds__(256) void conv_w(const float* __restrict__ Wq,
                                              const float* __restrict__ Wk,
                                              const float* __restrict__ Wv,
                                              short* __restrict__ wbf) {
  int o = blockIdx.x * 256 + threadIdx.x;  // 2304*768 total
  int n = o / DD, d = o % DD;
  int proj = n / HK;
  int hk = n % HK;
  int h = hk >> 6, k = hk & 63;
  const float* W = proj == 0 ? Wq : (proj == 1 ? Wk : Wv);
  float v = W[(size_t)h * DD * KK + (size_t)d * KK + k];
  if (proj == 0) v *= 0.125f * 1.44269504088896340736f;
  wbf[o] = f2bf(v);
}

// ---------------------------------------------------------------------------
// QKV GEMM (unchanged): C[m][n] = sum_d xbf[m][d] * wT[n][d].
// V (proj 2) written TRANSPOSED: Vt[bh][k][s].
// ---------------------------------------------------------------------------
__global__ __launch_bounds__(256) void qkv_gemm(const short* __restrict__ xbf,
                                                const short* __restrict__ wbf,
                                                short* __restrict__ qkv) {
  __shared__ short As[128 * 64];
  __shared__ short Bs[128 * 64];
  int bm = blockIdx.x & 63, bn = blockIdx.x >> 6;
  int m0 = bm * 128, n0 = bn * 128;
  int tid = threadIdx.x, lane = tid & 63, wid = tid >> 6;
  int li = lane & 15, lg = lane >> 4;
  int wm = wid >> 1, wn = wid & 1;

  f32x4 acc[4][4];
  #pragma unroll
  for (int mi = 0; mi < 4; ++mi)
    #pragma unroll
    for (int ni = 0; ni < 4; ++ni)
      acc[mi][ni] = (f32x4){0.f, 0.f, 0.f, 0.f};

  int rowoff = lane >> 3;
  int kp = (lane & 7) * 8;

  for (int kt = 0; kt < DD / 64; ++kt) {
    #pragma unroll
    for (int j = 0; j < 4; ++j) {
      int eb = wid * 2048 + j * 512;
      int row = (eb >> 6) + rowoff;
      __builtin_amdgcn_global_load_lds(
          (const __attribute__((address_space(1))) void*)(
              xbf + (size_t)(m0 + row) * DD + kt * 64 + kp),
          (__attribute__((address_space(3))) void*)(As + eb), 16, 0, 0);
      __builtin_amdgcn_global_load_lds(
          (const __attribute__((address_space(1))) void*)(
              wbf + (size_t)(n0 + row) * DD + kt * 64 + kp),
          (__attribute__((address_space(3))) void*)(Bs + eb), 16, 0, 0);
    }
    __syncthreads();

    #pragma unroll
    for (int kk = 0; kk < 2; ++kk) {
      bf16x8 af[4], bfr[4];
      #pragma unroll
      for (int mi = 0; mi < 4; ++mi)
        af[mi] = *(const bf16x8*)(As + (wm * 64 + mi * 16 + li) * 64 +
                                  kk * 32 + lg * 8);
      #pragma unroll
      for (int ni = 0; ni < 4; ++ni)
        bfr[ni] = *(const bf16x8*)(Bs + (wn * 64 + ni * 16 + li) * 64 +
                                   kk * 32 + lg * 8);
      #pragma unroll
      for (int mi = 0; mi < 4; ++mi)
        #pragma unroll
        for (int ni = 0; ni < 4; ++ni)
          acc[mi][ni] = __builtin_amdgcn_mfma_f32_16x16x32_bf16(
              af[mi], bfr[ni], acc[mi][ni], 0, 0, 0);
    }
    __syncthreads();
  }

  int proj = n0 / HK;
  #pragma unroll
  for (int ni = 0; ni < 4; ++ni) {
    int ncol = n0 + wn * 64 + ni * 16 + li;
    int hk = ncol % HK;
    int h = hk >> 6, k = hk & 63;
    #pragma unroll
    for (int mi = 0; mi < 4; ++mi) {
      int mrow0 = m0 + wm * 64 + mi * 16 + lg * 4;
      int b = mrow0 >> 11, s = mrow0 & 2047;
      if (proj == 2) {
        bf16x4 o = {f2bf(acc[mi][ni][0]), f2bf(acc[mi][ni][1]),
                    f2bf(acc[mi][ni][2]), f2bf(acc[mi][ni][3])};
        *(bf16x4*)(qkv + 2 * (size_t)PER +
                   ((size_t)(b * HH + h) * KK + k) * SS + s) = o;
      } else {
        #pragma unroll
        for (int r = 0; r < 4; ++r)
          qkv[(size_t)proj * PER +
              ((size_t)(b * HH + h) * SS + s + r) * KK + k] =
              f2bf(acc[mi][ni][r]);
      }
    }
  }
}

// ---------------------------------------------------------------------------
// One 32x32 flash step (exp2 domain, defer-max THR=11).
// sc C-layout: col=lane&31=q, row=key=crow(r,hi)=(r&3)+8*(r>>2)+4*hi.
// ---------------------------------------------------------------------------
static __device__ __forceinline__ void attn_step(
    const bf16x8* kf, const bf16x8 (*vf)[2], const bf16x8* qf, bool diag,
    int lq, int hi, float& m, float& lsum, f32x16& acc0, f32x16& acc1) {
  f32x16 sc;
  #pragma unroll
  for (int r = 0; r < 16; ++r) sc[r] = 0.f;
  __builtin_amdgcn_s_setprio(1);
  #pragma unroll
  for (int c = 0; c < 4; ++c)
    sc = __builtin_amdgcn_mfma_f32_32x32x16_bf16(kf[c], qf[c], sc, 0, 0, 0);
  __builtin_amdgcn_s_setprio(0);

  if (diag) {
    #pragma unroll
    for (int r = 0; r < 16; ++r) {
      int crow = (r & 3) + 8 * (r >> 2) + 4 * hi;
      if (crow > lq) sc[r] = -INFINITY;
    }
  }

  // max: pairwise tree
  float t8[8];
  #pragma unroll
  for (int r = 0; r < 8; ++r) t8[r] = fmaxf(sc[2 * r], sc[2 * r + 1]);
  float t4a = fmaxf(t8[0], t8[1]), t4b = fmaxf(t8[2], t8[3]);
  float t4c = fmaxf(t8[4], t8[5]), t4d = fmaxf(t8[6], t8[7]);
  float tm = fmaxf(fmaxf(t4a, t4b), fmaxf(t4c, t4d));
  tm = fmaxf(tm, __shfl_xor(tm, 32, 64));

  if (!__all(tm <= m + 11.f)) {  // defer-max (exp2 domain)
    float nm = fmaxf(m, tm);
    float corr = fexp2(m - nm);
    m = nm;
    lsum *= corr;
    #pragma unroll
    for (int r = 0; r < 16; ++r) {
      acc0[r] *= corr;
      acc1[r] *= corr;
    }
  }

  float p[16];
  #pragma unroll
  for (int r = 0; r < 16; ++r) p[r] = fexp2(sc[r] - m);
  float s8[8];
  #pragma unroll
  for (int r = 0; r < 8; ++r) s8[r] = p[2 * r] + p[2 * r + 1];
  float s4a = s8[0] + s8[1], s4b = s8[2] + s8[3];
  float s4c = s8[4] + s8[5], s4d = s8[6] + s8[7];
  float ps = (s4a + s4b) + (s4c + s4d);
  ps += __shfl_xor(ps, 32, 64);
  lsum += ps;

  // P fragments (B of O^T): cvt_pk + permlane32_swap
  bf16x8 pf[2];
  #pragma unroll
  for (int c = 0; c < 2; ++c) {
    unsigned a0 = cvtpk(p[8 * c + 0], p[8 * c + 1]);
    unsigned b0 = cvtpk(p[8 * c + 4], p[8 * c + 5]);
    unsigned a1 = cvtpk(p[8 * c + 2], p[8 * c + 3]);
    unsigned b1 = cvtpk(p[8 * c + 6], p[8 * c + 7]);
    asm volatile("v_permlane32_swap_b32 %0, %1" : "+v"(a0), "+v"(b0));
    asm volatile("v_permlane32_swap_b32 %0, %1" : "+v"(a1), "+v"(b1));
    union { unsigned u[4]; bf16x8 v; } pu;
    pu.u[0] = a0; pu.u[1] = a1; pu.u[2] = b0; pu.u[3] = b1;
    pf[c] = pu.v;
  }

  __builtin_amdgcn_s_setprio(1);
  acc0 = __builtin_amdgcn_mfma_f32_32x32x16_bf16(vf[0][0], pf[0], acc0, 0, 0, 0);
  acc0 = __builtin_amdgcn_mfma_f32_32x32x16_bf16(vf[0][1], pf[1], acc0, 0, 0, 0);
  acc1 = __builtin_amdgcn_mfma_f32_32x32x16_bf16(vf[1][0], pf[0], acc1, 0, 0, 0);
  acc1 = __builtin_amdgcn_mfma_f32_32x32x16_bf16(vf[1][1], pf[1], acc1, 0, 0, 0);
  __builtin_amdgcn_s_setprio(0);
}

// ---------------------------------------------------------------------------
// Flash attention, 32x32 MFMA, intra-block 4-way split-K, one-iteration
// register prefetch of next tile's K/V (hides L2 latency under compute).
// Block = one 32-query group; wave w handles tiles tt = w, w+4, ...
// Partials merged via LDS (flash-decode combine).
// ---------------------------------------------------------------------------
__global__ __launch_bounds__(256) void attn_kernel(
    const short* __restrict__ qkv, float* __restrict__ out) {
  __shared__ float accL[4][32][68];
  __shared__ float mlL[4][2][32];

  int wid = threadIdx.x >> 6, lane = threadIdx.x & 63;
  int bh = blockIdx.x % 48;          // qg-major: heaviest groups first
  int qg = 63 - (blockIdx.x / 48);
  int b = bh / HH, h = bh % HH;
  int s0 = qg * 32;
  int lq = lane & 31;                // query column
  int hi = lane >> 5;

  const short* Qb = qkv + (size_t)bh * SS * KK;
  const short* Kb = qkv + (size_t)PER + (size_t)bh * SS * KK;
  const short* Vt = qkv + 2 * (size_t)PER + (size_t)bh * KK * SS;

  bf16x8 qf[4];
  #pragma unroll
  for (int c = 0; c < 4; ++c)
    qf[c] = *(const bf16x8*)(Qb + (size_t)(s0 + lq) * KK + c * 16 + hi * 8);

  f32x16 acc0, acc1;
  #pragma unroll
  for (int r = 0; r < 16; ++r) { acc0[r] = 0.f; acc1[r] = 0.f; }
  float m = -INFINITY, lsum = 0.f;

  int tt = wid;
  if (tt <= qg) {
    int t0 = tt * 32;
    bf16x8 kc[4], vc[2][2];
    #pragma unroll
    for (int c = 0; c < 4; ++c)
      kc[c] = *(const bf16x8*)(Kb + (size_t)(t0 + lq) * KK + c * 16 + hi * 8);
    #pragma unroll
    for (int m2 = 0; m2 < 2; ++m2)
      #pragma unroll
      for (int c = 0; c < 2; ++c)
        vc[m2][c] = *(const bf16x8*)(Vt + (size_t)(32 * m2 + lq) * SS + t0 +
                                     c * 16 + hi * 8);

    for (; tt <= qg; tt += 4) {
      // prefetch next tile (clamped, branchless)
      int tn = (tt + 4 <= qg ? tt + 4 : tt) * 32;
      bf16x8 kn[4], vn[2][2];
      #pragma unroll
      for (int c = 0; c < 4; ++c)
        kn[c] =
            *(const bf16x8*)(Kb + (size_t)(tn + lq) * KK + c * 16 + hi * 8);
      #pragma unroll
      for (int m2 = 0; m2 < 2; ++m2)
        #pragma unroll
        for (int c = 0; c < 2; ++c)
          vn[m2][c] = *(const bf16x8*)(Vt + (size_t)(32 * m2 + lq) * SS + tn +
                                       c * 16 + hi * 8);

      attn_step(kc, vc, qf, tt == qg, lq, hi, m, lsum, acc0, acc1);

      #pragma unroll
      for (int c = 0; c < 4; ++c) kc[c] = kn[c];
      #pragma unroll
      for (int m2 = 0; m2 < 2; ++m2)
        #pragma unroll
        for (int c = 0; c < 2; ++c) vc[m2][c] = vn[m2][c];
    }
  }

  // ---- write wave partial: q=lq, kd=32*m2+crow(g-reg,hi) ----
  #pragma unroll
  for (int g = 0; g < 4; ++g) {
    f32x4 v0, v1;
    #pragma unroll
    for (int r = 0; r < 4; ++r) {
      v0[r] = acc0[g * 4 + r];
      v1[r] = acc1[g * 4 + r];
    }
    *(f32x4*)&accL[wid][lq][8 * g + 4 * hi] = v0;
    *(f32x4*)&accL[wid][lq][32 + 8 * g + 4 * hi] = v1;
  }
  if (hi == 0) {
    mlL[wid][0][lq] = m;
    mlL[wid][1][lq] = lsum;
  }
  __syncthreads();

  // ---- merge (flash-decode combine): wave w -> queries 8w..8w+7 ----
  {
    int q = 8 * wid + (lane >> 3);
    int kd = (lane & 7) * 8;
    float M = -INFINITY;
    #pragma unroll
    for (int v = 0; v < 4; ++v) M = fmaxf(M, mlL[v][0][q]);
    float scw[4], L = 0.f;
    #pragma unroll
    for (int v = 0; v < 4; ++v) {
      float mv = mlL[v][0][q];
      scw[v] = (mv > -INFINITY) ? fexp2(mv - M) : 0.f;
      L += mlL[v][1][q] * scw[v];
    }
    float inv = 1.0f / L;
    float o[8];
    #pragma unroll
    for (int j = 0; j < 8; ++j) o[j] = 0.f;
    #pragma unroll
    for (int v = 0; v < 4; ++v) {
      f32x4 a0 = *(const f32x4*)&accL[v][q][kd];
      f32x4 a1 = *(const f32x4*)&accL[v][q][kd + 4];
      #pragma unroll
      for (int j = 0; j < 4; ++j) {
        o[j] += a0[j] * scw[v];
        o[4 + j] += a1[j] * scw[v];
      }
    }
    float* orow = out + ((size_t)(b * SS + s0 + q)) * HK + h * KK + kd;
    float4 w0 = {o[0] * inv, o[1] * inv, o[2] * inv, o[3] * inv};
    float4 w1 = {o[4] * inv, o[5] * inv, o[6] * inv, o[7] * inv};
    *(float4*)(orow) = w0;
    *(float4*)(orow + 4) = w1;
  }
}

// ---------------------------------------------------------------------------
extern "C" void kernel_launch(void* const* d_in, const int* in_sizes, int n_in,
                              void* d_out, int out_size, void* d_ws,
                              size_t ws_size, hipStream_t stream) {
  const float* x  = (const float*)d_in[0];
  const float* Wq = (const float*)d_in[1];
  const float* Wk = (const float*)d_in[2];
  const float* Wv = (const float*)d_in[3];
  short* ws  = (short*)d_ws;
  short* qkv = ws;                       // 3 * PER shorts
  short* xbf = ws + (size_t)3 * PER;     // MROWS*DD shorts
  short* wbf = xbf + (size_t)MROWS * DD; // NCOLS*DD shorts
  float* o   = (float*)d_out;

  conv_x<<<(MROWS * DD) / 4 / 256, 256, 0, stream>>>(x, xbf);
  conv_w<<<(NCOLS * DD) / 256, 256, 0, stream>>>(Wq, Wk, Wv, wbf);
  qkv_gemm<<<(MROWS / 128) * (NCOLS / 128), 256, 0, stream>>>(xbf, wbf, qkv);
  attn_kernel<<<48 * 64, 256, 0, stream>>>(ws, o);
}

// Round 9
// 179.716 us; speedup vs baseline: 1.1459x; 1.0606x over previous
//
#include <hip/hip_runtime.h>
#include <math.h>

#define BB 4
#define SS 2048
#define DD 768
#define HH 12
#define KK 64

#define NPROJ 3
#define HK    (HH * KK)          // 768
#define NCOLS (NPROJ * HK)       // 2304
#define MROWS (BB * SS)          // 8192
#define PER   (BB * HH * SS * KK)  // 6291456 elements per proj

typedef __attribute__((ext_vector_type(8))) short bf16x8;
typedef __attribute__((ext_vector_type(4))) short bf16x4;
typedef __attribute__((ext_vector_type(4))) float f32x4;
typedef __attribute__((ext_vector_type(16))) float f32x16;

static __device__ __forceinline__ short f2bf(float f) {
  union { float f; unsigned u; } v;
  v.f = f;
  unsigned r = (v.u + 0x7fff + ((v.u >> 16) & 1)) >> 16;  // RNE
  return (short)r;
}

static __device__ __forceinline__ float bf2f(short s) {
  union { unsigned u; float f; } v;
  v.u = ((unsigned)(unsigned short)s) << 16;
  return v.f;
}

static __device__ __forceinline__ unsigned cvtpk(float lo, float hi) {
  unsigned r;
  asm("v_cvt_pk_bf16_f32 %0, %1, %2" : "=v"(r) : "v"(lo), "v"(hi));
  return r;
}

static __device__ __forceinline__ float fexp2(float x) {
#if __has_builtin(__builtin_amdgcn_exp2f)
  return __builtin_amdgcn_exp2f(x);
#else
  return exp2f(x);
#endif
}

static __device__ __forceinline__ float max3f(float a, float b, float c) {
  return fmaxf(fmaxf(a, b), c);  // clang fuses to v_max3_f32
}

// ---------------------------------------------------------------------------
// x (fp32) -> bf16, flat copy. 4 elems/thread.
// ---------------------------------------------------------------------------
__global__ __launch_bounds__(256) void conv_x(const float* __restrict__ x,
                                              short* __restrict__ xbf) {
  int i = (blockIdx.x * 256 + threadIdx.x) * 4;
  float4 v = *(const float4*)(x + i);
  bf16x4 o = {f2bf(v.x), f2bf(v.y), f2bf(v.z), f2bf(v.w)};
  *(bf16x4*)(xbf + i) = o;
}

// ---------------------------------------------------------------------------
// W -> bf16 transposed wT[n][d]. Q gets 1/sqrt(64) * log2(e) folded in
// (softmax runs in exp2 domain).
// ---------------------------------------------------------------------------
__global__ __launch_bounds__(256) void conv_w(const float* __restrict__ Wq,
                                              const float* __restrict__ Wk,
                                              const float* __restrict__ Wv,
                                              short* __restrict__ wbf) {
  int o = blockIdx.x * 256 + threadIdx.x;  // 2304*768 total
  int n = o / DD, d = o % DD;
  int proj = n / HK;
  int hk = n % HK;
  int h = hk >> 6, k = hk & 63;
  const float* W = proj == 0 ? Wq : (proj == 1 ? Wk : Wv);
  float v = W[(size_t)h * DD * KK + (size_t)d * KK + k];
  if (proj == 0) v *= 0.125f * 1.44269504088896340736f;
  wbf[o] = f2bf(v);
}

// ---------------------------------------------------------------------------
// QKV GEMM (unchanged): C[m][n] = sum_d xbf[m][d] * wT[n][d].
// V (proj 2) written TRANSPOSED: Vt[bh][k][s].
// ---------------------------------------------------------------------------
__global__ __launch_bounds__(256) void qkv_gemm(const short* __restrict__ xbf,
                                                const short* __restrict__ wbf,
                                                short* __restrict__ qkv) {
  __shared__ short As[128 * 64];
  __shared__ short Bs[128 * 64];
  int bm = blockIdx.x & 63, bn = blockIdx.x >> 6;
  int m0 = bm * 128, n0 = bn * 128;
  int tid = threadIdx.x, lane = tid & 63, wid = tid >> 6;
  int li = lane & 15, lg = lane >> 4;
  int wm = wid >> 1, wn = wid & 1;

  f32x4 acc[4][4];
  #pragma unroll
  for (int mi = 0; mi < 4; ++mi)
    #pragma unroll
    for (int ni = 0; ni < 4; ++ni)
      acc[mi][ni] = (f32x4){0.f, 0.f, 0.f, 0.f};

  int rowoff = lane >> 3;
  int kp = (lane & 7) * 8;

  for (int kt = 0; kt < DD / 64; ++kt) {
    #pragma unroll
    for (int j = 0; j < 4; ++j) {
      int eb = wid * 2048 + j * 512;
      int row = (eb >> 6) + rowoff;
      __builtin_amdgcn_global_load_lds(
          (const __attribute__((address_space(1))) void*)(
              xbf + (size_t)(m0 + row) * DD + kt * 64 + kp),
          (__attribute__((address_space(3))) void*)(As + eb), 16, 0, 0);
      __builtin_amdgcn_global_load_lds(
          (const __attribute__((address_space(1))) void*)(
              wbf + (size_t)(n0 + row) * DD + kt * 64 + kp),
          (__attribute__((address_space(3))) void*)(Bs + eb), 16, 0, 0);
    }
    __syncthreads();

    #pragma unroll
    for (int kk = 0; kk < 2; ++kk) {
      bf16x8 af[4], bfr[4];
      #pragma unroll
      for (int mi = 0; mi < 4; ++mi)
        af[mi] = *(const bf16x8*)(As + (wm * 64 + mi * 16 + li) * 64 +
                                  kk * 32 + lg * 8);
      #pragma unroll
      for (int ni = 0; ni < 4; ++ni)
        bfr[ni] = *(const bf16x8*)(Bs + (wn * 64 + ni * 16 + li) * 64 +
                                   kk * 32 + lg * 8);
      #pragma unroll
      for (int mi = 0; mi < 4; ++mi)
        #pragma unroll
        for (int ni = 0; ni < 4; ++ni)
          acc[mi][ni] = __builtin_amdgcn_mfma_f32_16x16x32_bf16(
              af[mi], bfr[ni], acc[mi][ni], 0, 0, 0);
    }
    __syncthreads();
  }

  int proj = n0 / HK;
  #pragma unroll
  for (int ni = 0; ni < 4; ++ni) {
    int ncol = n0 + wn * 64 + ni * 16 + li;
    int hk = ncol % HK;
    int h = hk >> 6, k = hk & 63;
    #pragma unroll
    for (int mi = 0; mi < 4; ++mi) {
      int mrow0 = m0 + wm * 64 + mi * 16 + lg * 4;
      int b = mrow0 >> 11, s = mrow0 & 2047;
      if (proj == 2) {
        bf16x4 o = {f2bf(acc[mi][ni][0]), f2bf(acc[mi][ni][1]),
                    f2bf(acc[mi][ni][2]), f2bf(acc[mi][ni][3])};
        *(bf16x4*)(qkv + 2 * (size_t)PER +
                   ((size_t)(b * HH + h) * KK + k) * SS + s) = o;
      } else {
        #pragma unroll
        for (int r = 0; r < 4; ++r)
          qkv[(size_t)proj * PER +
              ((size_t)(b * HH + h) * SS + s + r) * KK + k] =
              f2bf(acc[mi][ni][r]);
      }
    }
  }
}

// ---------------------------------------------------------------------------
// One 32x32 flash step (exp2 domain, defer-max THR=11).
// sc C-layout: col=lane&31=q, row=key=crow(r,hi)=(r&3)+8*(r>>2)+4*hi.
// ---------------------------------------------------------------------------
static __device__ __forceinline__ void attn_step(
    const bf16x8* kf, const bf16x8 (*vf)[2], const bf16x8* qf, bool diag,
    int lq, int hi, float& m, float& lsum, f32x16& acc0, f32x16& acc1) {
  f32x16 sc;
  #pragma unroll
  for (int r = 0; r < 16; ++r) sc[r] = 0.f;
  #pragma unroll
  for (int c = 0; c < 4; ++c)
    sc = __builtin_amdgcn_mfma_f32_32x32x16_bf16(kf[c], qf[c], sc, 0, 0, 0);

  if (diag) {
    #pragma unroll
    for (int r = 0; r < 16; ++r) {
      int crow = (r & 3) + 8 * (r >> 2) + 4 * hi;
      if (crow > lq) sc[r] = -INFINITY;
    }
  }

  // max via max3 tree: 16 -> 6 -> 2 -> 1
  float a0 = max3f(sc[0], sc[1], sc[2]);
  float a1 = max3f(sc[3], sc[4], sc[5]);
  float a2 = max3f(sc[6], sc[7], sc[8]);
  float a3 = max3f(sc[9], sc[10], sc[11]);
  float a4 = max3f(sc[12], sc[13], sc[14]);
  float b0 = max3f(a0, a1, a2);
  float b1 = max3f(a3, a4, sc[15]);
  float tm = fmaxf(b0, b1);
  tm = fmaxf(tm, __shfl_xor(tm, 32, 64));

  if (!__all(tm <= m + 11.f)) {  // defer-max (exp2 domain)
    float nm = fmaxf(m, tm);
    float corr = fexp2(m - nm);
    m = nm;
    lsum *= corr;
    #pragma unroll
    for (int r = 0; r < 16; ++r) {
      acc0[r] *= corr;
      acc1[r] *= corr;
    }
  }

  float p[16];
  #pragma unroll
  for (int r = 0; r < 16; ++r) p[r] = fexp2(sc[r] - m);
  float s8[8];
  #pragma unroll
  for (int r = 0; r < 8; ++r) s8[r] = p[2 * r] + p[2 * r + 1];
  float s4a = s8[0] + s8[1], s4b = s8[2] + s8[3];
  float s4c = s8[4] + s8[5], s4d = s8[6] + s8[7];
  float ps = (s4a + s4b) + (s4c + s4d);
  ps += __shfl_xor(ps, 32, 64);
  lsum += ps;

  // P fragments (B of O^T): cvt_pk + permlane32_swap
  bf16x8 pf[2];
  #pragma unroll
  for (int c = 0; c < 2; ++c) {
    unsigned a0u = cvtpk(p[8 * c + 0], p[8 * c + 1]);
    unsigned b0u = cvtpk(p[8 * c + 4], p[8 * c + 5]);
    unsigned a1u = cvtpk(p[8 * c + 2], p[8 * c + 3]);
    unsigned b1u = cvtpk(p[8 * c + 6], p[8 * c + 7]);
    asm volatile("v_permlane32_swap_b32 %0, %1" : "+v"(a0u), "+v"(b0u));
    asm volatile("v_permlane32_swap_b32 %0, %1" : "+v"(a1u), "+v"(b1u));
    union { unsigned u[4]; bf16x8 v; } pu;
    pu.u[0] = a0u; pu.u[1] = a1u; pu.u[2] = b0u; pu.u[3] = b1u;
    pf[c] = pu.v;
  }

  acc0 = __builtin_amdgcn_mfma_f32_32x32x16_bf16(vf[0][0], pf[0], acc0, 0, 0, 0);
  acc0 = __builtin_amdgcn_mfma_f32_32x32x16_bf16(vf[0][1], pf[1], acc0, 0, 0, 0);
  acc1 = __builtin_amdgcn_mfma_f32_32x32x16_bf16(vf[1][0], pf[0], acc1, 0, 0, 0);
  acc1 = __builtin_amdgcn_mfma_f32_32x32x16_bf16(vf[1][1], pf[1], acc1, 0, 0, 0);
}

// ---------------------------------------------------------------------------
// Flash attention, 32x32 MFMA, intra-block 4-way split-K.
// Block = one 32-query group; wave w handles tiles tt = w, w+4, ...
// Partials stored in LDS as BF16 (halves LDS -> 8 blocks/CU occupancy
// ceiling); merged via flash-decode combine. Direct loads, no prefetch.
// ---------------------------------------------------------------------------
__global__ __launch_bounds__(256) void attn_kernel(
    const short* __restrict__ qkv, float* __restrict__ out) {
  __shared__ short accL[4][32][72];   // bf16 partials, 72-short rows (16B ok)
  __shared__ float mlL[4][2][32];

  int wid = threadIdx.x >> 6, lane = threadIdx.x & 63;
  int bh = blockIdx.x % 48;          // qg-major: heaviest groups first
  int qg = 63 - (blockIdx.x / 48);
  int b = bh / HH, h = bh % HH;
  int s0 = qg * 32;
  int lq = lane & 31;                // query column
  int hi = lane >> 5;

  const short* Qb = qkv + (size_t)bh * SS * KK;
  const short* Kb = qkv + (size_t)PER + (size_t)bh * SS * KK;
  const short* Vt = qkv + 2 * (size_t)PER + (size_t)bh * KK * SS;

  bf16x8 qf[4];
  #pragma unroll
  for (int c = 0; c < 4; ++c)
    qf[c] = *(const bf16x8*)(Qb + (size_t)(s0 + lq) * KK + c * 16 + hi * 8);

  f32x16 acc0, acc1;
  #pragma unroll
  for (int r = 0; r < 16; ++r) { acc0[r] = 0.f; acc1[r] = 0.f; }
  float m = -INFINITY, lsum = 0.f;

  for (int tt = wid; tt <= qg; tt += 4) {
    int t0 = tt * 32;
    bf16x8 kf[4];
    #pragma unroll
    for (int c = 0; c < 4; ++c)
      kf[c] = *(const bf16x8*)(Kb + (size_t)(t0 + lq) * KK + c * 16 + hi * 8);
    bf16x8 vf[2][2];
    #pragma unroll
    for (int m2 = 0; m2 < 2; ++m2)
      #pragma unroll
      for (int c = 0; c < 2; ++c)
        vf[m2][c] = *(const bf16x8*)(Vt + (size_t)(32 * m2 + lq) * SS + t0 +
                                     c * 16 + hi * 8);
    attn_step(kf, vf, qf, tt == qg, lq, hi, m, lsum, acc0, acc1);
  }

  // ---- write wave partial as bf16: q=lq, kd=32*m2+8g+4hi+rr ----
  #pragma unroll
  for (int g = 0; g < 4; ++g) {
    unsigned u0 = cvtpk(acc0[g * 4 + 0], acc0[g * 4 + 1]);
    unsigned u1 = cvtpk(acc0[g * 4 + 2], acc0[g * 4 + 3]);
    unsigned w0 = cvtpk(acc1[g * 4 + 0], acc1[g * 4 + 1]);
    unsigned w1 = cvtpk(acc1[g * 4 + 2], acc1[g * 4 + 3]);
    union { unsigned u[2]; bf16x4 v; } p0, p1;
    p0.u[0] = u0; p0.u[1] = u1;
    p1.u[0] = w0; p1.u[1] = w1;
    *(bf16x4*)&accL[wid][lq][8 * g + 4 * hi] = p0.v;
    *(bf16x4*)&accL[wid][lq][32 + 8 * g + 4 * hi] = p1.v;
  }
  if (hi == 0) {
    mlL[wid][0][lq] = m;
    mlL[wid][1][lq] = lsum;
  }
  __syncthreads();

  // ---- merge (flash-decode combine): wave w -> queries 8w..8w+7 ----
  {
    int q = 8 * wid + (lane >> 3);
    int kd = (lane & 7) * 8;
    float M = -INFINITY;
    #pragma unroll
    for (int v = 0; v < 4; ++v) M = fmaxf(M, mlL[v][0][q]);
    float scw[4], L = 0.f;
    #pragma unroll
    for (int v = 0; v < 4; ++v) {
      float mv = mlL[v][0][q];
      scw[v] = (mv > -INFINITY) ? fexp2(mv - M) : 0.f;
      L += mlL[v][1][q] * scw[v];
    }
    float inv = 1.0f / L;
    float o[8];
    #pragma unroll
    for (int j = 0; j < 8; ++j) o[j] = 0.f;
    #pragma unroll
    for (int v = 0; v < 4; ++v) {
      bf16x8 a = *(const bf16x8*)&accL[v][q][kd];
      #pragma unroll
      for (int j = 0; j < 8; ++j) o[j] += bf2f(a[j]) * scw[v];
    }
    float* orow = out + ((size_t)(b * SS + s0 + q)) * HK + h * KK + kd;
    float4 w0 = {o[0] * inv, o[1] * inv, o[2] * inv, o[3] * inv};
    float4 w1 = {o[4] * inv, o[5] * inv, o[6] * inv, o[7] * inv};
    *(float4*)(orow) = w0;
    *(float4*)(orow + 4) = w1;
  }
}

// ---------------------------------------------------------------------------
extern "C" void kernel_launch(void* const* d_in, const int* in_sizes, int n_in,
                              void* d_out, int out_size, void* d_ws,
                              size_t ws_size, hipStream_t stream) {
  const float* x  = (const float*)d_in[0];
  const float* Wq = (const float*)d_in[1];
  const float* Wk = (const float*)d_in[2];
  const float* Wv = (const float*)d_in[3];
  short* ws  = (short*)d_ws;
  short* qkv = ws;                       // 3 * PER shorts
  short* xbf = ws + (size_t)3 * PER;     // MROWS*DD shorts
  short* wbf = xbf + (size_t)MROWS * DD; // NCOLS*DD shorts
  float* o   = (float*)d_out;

  conv_x<<<(MROWS * DD) / 4 / 256, 256, 0, stream>>>(x, xbf);
  conv_w<<<(NCOLS * DD) / 256, 256, 0, stream>>>(Wq, Wk, Wv, wbf);
  qkv_gemm<<<(MROWS / 128) * (NCOLS / 128), 256, 0, stream>>>(xbf, wbf, qkv);
  attn_kernel<<<48 * 64, 256, 0, stream>>>(ws, o);
}